// Round 9
// baseline (267.443 us; speedup 1.0000x reference)
//
#include <hip/hip_runtime.h>

// x [16384,512] f32, codebook [8192,512] f32 -> out[n] = codebook[argmin_k ||x_n-c_k||^2]
// 256x256 bf16 MFMA GEMM with m201-faithful 8-phase schedule: per phase
// {ds_reads(this phase) | stage 1 unit | counted vmcnt} -> s_barrier -> lgkmcnt(0) ->
// setprio+16 MFMA -> s_barrier. Operand-swapped (A=codebook, B=x) so argmin axis is
// lane-local; per-lane register top-3 epilogue; guaranteed-inclusive fp64 refine (+fused
// gather when ws allows); gather fallback.

#define MROWS 16384
#define KCB   8192
#define DDIM  512
#define NTILES (KCB / 128)   // 64 stat tiles of 128 cols
#define MARGIN 8.0f

typedef unsigned short u16;
typedef unsigned int uint;
typedef __attribute__((ext_vector_type(8))) short bf16x8;
typedef __attribute__((ext_vector_type(4))) float f32x4;

__device__ inline u16 f2bf(float f) {
  unsigned int u = __float_as_uint(f);
  u += 0x7FFFu + ((u >> 16) & 1u);
  return (u16)(u >> 16);
}

__device__ inline void gload16(const void* g, void* l) {
  __builtin_amdgcn_global_load_lds((const __attribute__((address_space(1))) void*)g,
                                   (__attribute__((address_space(3))) void*)l,
                                   16, 0, 0);
}

__device__ inline double shfl_xor_dbl(double v, int m) {
  long long l = __double_as_longlong(v);
  int lo = (int)(l & 0xffffffffLL), hi = (int)(l >> 32);
  lo = __shfl_xor(lo, m, 64);
  hi = __shfl_xor(hi, m, 64);
  return __longlong_as_double(((long long)hi << 32) | (unsigned long long)(unsigned int)lo);
}

__device__ inline float keyval(uint k) {
  uint u = k & 0xFFFFFF80u;
  uint bits = (u & 0x80000000u) ? (u & 0x7FFFFFFFu) : ~u;
  return __uint_as_float(bits);
}

// ---------------- conversion kernels ----------------

__global__ __launch_bounds__(256) void k_conv_x(const float* __restrict__ x,
                                                u16* __restrict__ xb) {
  size_t i = ((size_t)blockIdx.x * 256 + threadIdx.x) * 8;
  float4 a = *(const float4*)(x + i);
  float4 b = *(const float4*)(x + i + 4);
  union { u16 s[8]; uint4 v; } u;
  u.s[0]=f2bf(a.x); u.s[1]=f2bf(a.y); u.s[2]=f2bf(a.z); u.s[3]=f2bf(a.w);
  u.s[4]=f2bf(b.x); u.s[5]=f2bf(b.y); u.s[6]=f2bf(b.z); u.s[7]=f2bf(b.w);
  *(uint4*)(xb + i) = u.v;
}

__global__ __launch_bounds__(256) void k_conv_cb(const float* __restrict__ cb,
                                                 u16* __restrict__ cbb,
                                                 float* __restrict__ cnorm) {
  int k = blockIdx.x * 4 + (threadIdx.x >> 6);
  int lane = threadIdx.x & 63;
  size_t base = (size_t)k * DDIM + lane * 8;
  float4 a = *(const float4*)(cb + base);
  float4 b = *(const float4*)(cb + base + 4);
  union { u16 s[8]; uint4 v; } u;
  u.s[0]=f2bf(a.x); u.s[1]=f2bf(a.y); u.s[2]=f2bf(a.z); u.s[3]=f2bf(a.w);
  u.s[4]=f2bf(b.x); u.s[5]=f2bf(b.y); u.s[6]=f2bf(b.z); u.s[7]=f2bf(b.w);
  *(uint4*)(cbb + base) = u.v;
  float s = a.x*a.x + a.y*a.y + a.z*a.z + a.w*a.w
          + b.x*b.x + b.y*b.y + b.z*b.z + b.w*b.w;
  #pragma unroll
  for (int m = 1; m < 64; m <<= 1) s += __shfl_xor(s, m, 64);
  if (lane == 0) cnorm[k] = s;
}

// ---------------- 256x256 GEMM, m201-faithful 8-phase ----------------
// LDS (u16): A buf b [b*16384,+16384): h-region +h*8192, band w +w*4096, row +rr*64
// (rowwise XOR-8 16B-chunk swizzle). B buf b [32768+b*16384): [256][64].

__global__ __launch_bounds__(512, 2) void k_gemm_min(
    const u16* __restrict__ Xbf, const u16* __restrict__ Cbf,
    const float* __restrict__ cnorm, uint2* __restrict__ stats)
{
  extern __shared__ __align__(16) u16 lds[];

  int bid = blockIdx.x;          // 2048 blocks
  int xcd = bid & 7;
  int j   = bid >> 3;
  int mTile = xcd * 8 + (j & 7); // x-row tiles 0..63
  int nTile = j >> 3;            // cb tiles 0..31
  int rowBase = mTile * 256;     // x rows
  int colBase = nTile * 256;     // cb rows

  int tid = threadIdx.x;
  int lane = tid & 63;
  int wv = tid >> 6;     // 0..7
  int wr = wv >> 2;      // 0..1  cb half (MFMA A/M dim)
  int wc = wv & 3;       // 0..3  x quarter (MFMA B/N dim)
  int grp = lane >> 4;
  int l15 = lane & 15;

  // stage source base (inverse-swizzled global chunk)
  const int rr = tid >> 3;             // 0..63
  const int pc = (tid & 7) ^ (rr & 7);
  const u16* pA = Cbf + (size_t)(colBase + rr) * DDIM + pc * 8;
  const u16* pB = Xbf + (size_t)(rowBase + rr) * DDIM + pc * 8;

  // reader LDS offsets per k-slot
  const int m7 = l15 & 7;
  const int ch0 = (grp ^ m7);
  const int ch1 = ch0 ^ 4;
  const int cOff0 = wr * 4096 + l15 * 64 + ch0 * 8;
  const int cOff1 = wr * 4096 + l15 * 64 + ch1 * 8;
  const int xOff0 = wc * 4096 + l15 * 64 + ch0 * 8;
  const int xOff1 = wc * 4096 + l15 * 64 + ch1 * 8;

  f32x4 acc[8][4];
  #pragma unroll
  for (int mi = 0; mi < 8; ++mi)
    #pragma unroll
    for (int ni = 0; ni < 4; ++ni)
      acc[mi][ni] = (f32x4){0.f, 0.f, 0.f, 0.f};

  bf16x8 xF[2][4];   // indexed by ks; loaded at h==0 phases, reused at h==1

#define STAGE_AH0(T) { const int d_=((T)&1)*16384; const int so_=(T)*64;                  \
  gload16(pA + so_,          (void*)&lds[d_ + tid * 8]);                                  \
  gload16(pA + 65536 + so_,  (void*)&lds[d_ + 4096 + tid * 8]); }
#define STAGE_AH1(T) { const int d_=((T)&1)*16384 + 8192; const int so_=(T)*64;           \
  gload16(pA + 32768 + so_,  (void*)&lds[d_ + tid * 8]);                                  \
  gload16(pA + 98304 + so_,  (void*)&lds[d_ + 4096 + tid * 8]); }
#define STAGE_BH0(T) { const int d_=32768+((T)&1)*16384; const int so_=(T)*64;            \
  gload16(pB + so_,          (void*)&lds[d_ + tid * 8]);                                  \
  gload16(pB + 32768 + so_,  (void*)&lds[d_ + 4096 + tid * 8]); }
#define STAGE_BH1(T) { const int d_=32768+((T)&1)*16384 + 8192; const int so_=(T)*64;     \
  gload16(pB + 65536 + so_,  (void*)&lds[d_ + 4096 + tid * 8]);                           \
  gload16(pB + 98304 + so_,  (void*)&lds[d_ + 8192 + tid * 8]); }
// NOTE: BH1 dest layout must mirror stage rows 128..255 into B region h1 (+8192):
#undef STAGE_BH1
#define STAGE_BH1(T) { const int d_=32768+((T)&1)*16384 + 8192; const int so_=(T)*64;     \
  gload16(pB + 65536 + so_,  (void*)&lds[d_ + tid * 8]);                                  \
  gload16(pB + 98304 + so_,  (void*)&lds[d_ + 4096 + tid * 8]); }

  // ---- prologue: tile0 all (8) then tile1 h0 (4); certify tile0; barrier ----
  STAGE_AH0(0); STAGE_BH0(0); STAGE_AH1(0); STAGE_BH1(0);
  STAGE_AH0(1); STAGE_BH0(1);
  asm volatile("s_waitcnt vmcnt(4)" ::: "memory");
  __builtin_amdgcn_s_barrier();
  __builtin_amdgcn_sched_barrier(0);

  #pragma unroll 1
  for (int it = 0; it < 4; ++it) {
    const int t0 = 2 * it;
    #pragma unroll
    for (int p = 0; p < 8; ++p) {
      const int s = p & 3, h = s >> 1, ks = s & 1, bp = p >> 2;
      const int kt = t0 + bp;

      // ---- pre-barrier window: reads for THIS phase, one stage unit, vmcnt ----
      bf16x8 cF[4];
      {
        const int co_ = ks ? cOff1 : cOff0;
        #pragma unroll
        for (int q = 0; q < 4; ++q)
          cF[q] = *(const bf16x8*)&lds[bp * 16384 + h * 8192 + q * 1024 + co_];
        if (h == 0) {
          const int xo_ = ks ? xOff1 : xOff0;
          #pragma unroll
          for (int ni = 0; ni < 4; ++ni)
            xF[ks][ni] = *(const bf16x8*)&lds[32768 + bp * 16384 + ni * 1024 + xo_];
        }
      }
      if      (s == 0) { if (kt + 1 <= 7) STAGE_BH1(kt + 1); }
      else if (s == 1) { if (kt + 1 <= 7) STAGE_AH1(kt + 1); }
      else if (s == 2) { if (kt + 2 <= 7) STAGE_AH0(kt + 2); }
      else             { if (kt + 2 <= 7) STAGE_BH0(kt + 2); }

      if (ks == 1) {   // odd sub-phase: counted certification
        if (it == 3 && p == 3)      { asm volatile("s_waitcnt vmcnt(4)" ::: "memory"); }
        else if (it == 3 && p == 5) { asm volatile("s_waitcnt vmcnt(0)" ::: "memory"); }
        else if (!(it == 3 && p == 7)) { asm volatile("s_waitcnt vmcnt(8)" ::: "memory"); }
      }
      __builtin_amdgcn_sched_barrier(0);
      __builtin_amdgcn_s_barrier();
      asm volatile("s_waitcnt lgkmcnt(0)" ::: "memory");
      __builtin_amdgcn_sched_barrier(0);

      // ---- pure-MFMA region ----
      __builtin_amdgcn_s_setprio(1);
      #pragma unroll
      for (int q = 0; q < 4; ++q)
        #pragma unroll
        for (int ni = 0; ni < 4; ++ni)
          acc[h * 4 + q][ni] = __builtin_amdgcn_mfma_f32_16x16x32_bf16(
              cF[q], xF[ks][ni], acc[h * 4 + q][ni], 0, 0, 0);
      __builtin_amdgcn_s_setprio(0);
      __builtin_amdgcn_sched_barrier(0);
      __builtin_amdgcn_s_barrier();
    }
  }
#undef STAGE_AH0
#undef STAGE_AH1
#undef STAGE_BH0
#undef STAGE_BH1

  // ---- epilogue: per-lane register top-3 (rounds 6-8 verified) ----
  // D[m=cb][n=x]: x-row = lane&15, cb = (lane>>4)*4 + reg; acc[mi] <-> cb wr*128+mi*16
#define INS(st1, st2, st3, kx)                                     \
  { uint kk_ = (kx);                                               \
    bool lt1 = kk_ < st1, lt2 = kk_ < st2, lt3 = kk_ < st3;        \
    st3 = lt3 ? (lt2 ? st2 : kk_) : st3;                           \
    st2 = lt2 ? (lt1 ? st1 : kk_) : st2;                           \
    st1 = lt1 ? kk_ : st1; }

  uint t1[4], t2[4], t3[4];
  #pragma unroll
  for (int ni = 0; ni < 4; ++ni) { t1[ni] = 0xFFFFFFFFu; t2[ni] = 0xFFFFFFFFu; t3[ni] = 0xFFFFFFFFu; }

  #pragma unroll
  for (int mi = 0; mi < 8; ++mi) {
    float cnv[4];
    *(float4*)cnv = *(const float4*)&cnorm[colBase + wr * 128 + mi * 16 + grp * 4];
    #pragma unroll
    for (int ni = 0; ni < 4; ++ni) {
      #pragma unroll
      for (int rg = 0; rg < 4; ++rg) {
        float v = cnv[rg] - 2.0f * acc[mi][ni][rg];
        uint u = __float_as_uint(v);
        u = ((int)u < 0) ? ~u : (u | 0x80000000u);
        uint key = (u & 0xFFFFFF80u) | (uint)(mi * 16 + grp * 4 + rg);
        INS(t1[ni], t2[ni], t3[ni], key);
      }
    }
  }
  #pragma unroll
  for (int ni = 0; ni < 4; ++ni) {
    #pragma unroll
    for (int mk = 16; mk <= 32; mk <<= 1) {
      uint o1 = (uint)__shfl_xor((int)t1[ni], mk, 64);
      uint o2 = (uint)__shfl_xor((int)t2[ni], mk, 64);
      uint o3 = (uint)__shfl_xor((int)t3[ni], mk, 64);
      INS(t1[ni], t2[ni], t3[ni], o1);
      INS(t1[ni], t2[ni], t3[ni], o2);
      INS(t1[ni], t2[ni], t3[ni], o3);
    }
  }
#undef INS
  if (grp == 0) {
    #pragma unroll
    for (int ni = 0; ni < 4; ++ni) {
      float v1 = keyval(t1[ni]), v2 = keyval(t2[ni]), v3 = keyval(t3[ni]);
      uint i1 = t1[ni] & 127u, i2 = t2[ni] & 127u;
      uint d2 = min(255u, (uint)((v2 - v1) * 4.0f));
      uint d3 = min(255u, (uint)((v3 - v1) * 4.0f));
      uint2 st;
      st.x = __float_as_uint(v1);
      st.y = i1 | (i2 << 7) | (d2 << 14) | (d3 << 22);
      int xrow = rowBase + wc * 64 + ni * 16 + l15;
      stats[(size_t)xrow * NTILES + nTile * 2 + wr] = st;
    }
  }
}

// ---------------- fp64 refinement core ----------------

__device__ inline void eval64(const float4& xa, const float4& xb,
                              const float* __restrict__ cb, int col,
                              double& best, int& bi, int lane) {
  const float* cr = cb + (size_t)col * DDIM + lane * 8;
  float4 ca = *(const float4*)cr;
  float4 cv = *(const float4*)(cr + 4);
  double s = 0.0, d;
  d = (double)xa.x - (double)ca.x; s += d*d;
  d = (double)xa.y - (double)ca.y; s += d*d;
  d = (double)xa.z - (double)ca.z; s += d*d;
  d = (double)xa.w - (double)ca.w; s += d*d;
  d = (double)xb.x - (double)cv.x; s += d*d;
  d = (double)xb.y - (double)cv.y; s += d*d;
  d = (double)xb.z - (double)cv.z; s += d*d;
  d = (double)xb.w - (double)cv.w; s += d*d;
  #pragma unroll
  for (int m = 1; m < 64; m <<= 1) s += shfl_xor_dbl(s, m);
  if (s < best || (s == best && col < bi)) { best = s; bi = col; }
}

__device__ inline int refine_row(int n, int lane,
                                 const float* __restrict__ x, const float* __restrict__ cb,
                                 const float* __restrict__ cnorm,
                                 const uint2* __restrict__ stats) {
  uint2 st = stats[(size_t)n * NTILES + lane];
  float m1 = __uint_as_float(st.x);
  int   i1 = st.y & 127, i2 = (st.y >> 7) & 127;
  float m2 = m1 + ((st.y >> 14) & 255u) * 0.25f;
  float m3 = m1 + ((st.y >> 22) & 255u) * 0.25f;
  float g = m1;
  #pragma unroll
  for (int m = 1; m < 64; m <<= 1) g = fminf(g, __shfl_xor(g, m, 64));
  float T = g + MARGIN;
  unsigned long long q1 = __ballot(m1 <= T);
  unsigned long long q2 = __ballot(m2 <= T);
  unsigned long long qr = __ballot(m3 <= T);

  const float* xr = x + (size_t)n * DDIM;
  float4 xa = *(const float4*)(xr + lane * 8);
  float4 xb = *(const float4*)(xr + lane * 8 + 4);

  double best = 1e300;
  int bi = 0x7fffffff;

  while (q1) {
    int t = __ffsll(q1) - 1; q1 &= q1 - 1;
    int col = t * 128 + __shfl(i1, t, 64);
    eval64(xa, xb, cb, col, best, bi, lane);
  }
  while (q2) {
    int t = __ffsll(q2) - 1; q2 &= q2 - 1;
    int col = t * 128 + __shfl(i2, t, 64);
    eval64(xa, xb, cb, col, best, bi, lane);
  }
  while (qr) {
    int t = __ffsll(qr) - 1; qr &= qr - 1;
    for (int c2 = 0; c2 < 128; ++c2) {
      int col2 = t * 128 + c2;
      const float* cr = cb + (size_t)col2 * DDIM + lane * 8;
      float4 ca = *(const float4*)cr;
      float4 cv = *(const float4*)(cr + 4);
      float p = xa.x*ca.x + xa.y*ca.y + xa.z*ca.z + xa.w*ca.w
              + xb.x*cv.x + xb.y*cv.y + xb.z*cv.z + xb.w*cv.w;
      #pragma unroll
      for (int m = 1; m < 64; m <<= 1) p += __shfl_xor(p, m, 64);
      float s32 = cnorm[col2] - 2.0f * p;
      if (s32 <= T) {
        double s = 0.0, dd;
        dd = (double)xa.x - (double)ca.x; s += dd*dd;
        dd = (double)xa.y - (double)ca.y; s += dd*dd;
        dd = (double)xa.z - (double)ca.z; s += dd*dd;
        dd = (double)xa.w - (double)ca.w; s += dd*dd;
        dd = (double)xb.x - (double)cv.x; s += dd*dd;
        dd = (double)xb.y - (double)cv.y; s += dd*dd;
        dd = (double)xb.z - (double)cv.z; s += dd*dd;
        dd = (double)xb.w - (double)cv.w; s += dd*dd;
        #pragma unroll
        for (int m = 1; m < 64; m <<= 1) s += shfl_xor_dbl(s, m);
        if (s < best || (s == best && col2 < bi)) { best = s; bi = col2; }
      }
    }
  }
  return bi;   // identical across lanes (full-wave reductions)
}

__global__ __launch_bounds__(256) void k_refine(
    const float* __restrict__ x, const float* __restrict__ cb,
    const float* __restrict__ cnorm, const uint2* __restrict__ stats,
    unsigned int* __restrict__ bestOut)
{
  int n = blockIdx.x * 4 + (threadIdx.x >> 6);
  int lane = threadIdx.x & 63;
  int bi = refine_row(n, lane, x, cb, cnorm, stats);
  if (lane == 0) bestOut[n] = (unsigned int)bi;
}

__global__ __launch_bounds__(256) void k_refine_gather(
    const float* __restrict__ x, const float* __restrict__ cb,
    const float* __restrict__ cnorm, const uint2* __restrict__ stats,
    float* __restrict__ out)
{
  int n = blockIdx.x * 4 + (threadIdx.x >> 6);
  int lane = threadIdx.x & 63;
  int bi = refine_row(n, lane, x, cb, cnorm, stats);
  const float4* s = (const float4*)(cb + (size_t)bi * DDIM);
  float4* dp = (float4*)(out + (size_t)n * DDIM);
  dp[lane * 2]     = s[lane * 2];
  dp[lane * 2 + 1] = s[lane * 2 + 1];
}

// ---------------- gather (fallback) ----------------

__global__ __launch_bounds__(256) void k_gather(const float* __restrict__ cb,
                                                const unsigned int* __restrict__ bestIdx,
                                                float* __restrict__ out) {
  int n = blockIdx.x * 4 + (threadIdx.x >> 6);
  int lane = threadIdx.x & 63;
  unsigned int b = bestIdx[n];
  const float4* s = (const float4*)(cb + (size_t)b * DDIM);
  float4* dp = (float4*)(out + (size_t)n * DDIM);
  dp[lane * 2]     = s[lane * 2];
  dp[lane * 2 + 1] = s[lane * 2 + 1];
}

// ---------------- launch ----------------

extern "C" void kernel_launch(void* const* d_in, const int* in_sizes, int n_in,
                              void* d_out, int out_size, void* d_ws, size_t ws_size,
                              hipStream_t stream) {
  const float* x  = (const float*)d_in[0];   // [16384, 512]
  const float* cb = (const float*)d_in[1];   // [8192, 512]
  float* out = (float*)d_out;

  char* ob = (char*)d_out;
  u16* Xbf = (u16*)ob;                          // [0,16M)
  u16* Cbf = (u16*)(ob + 16ull * 1024 * 1024);  // [16M,24M)

  char* wsb = (char*)d_ws;
  float* cnorm = (float*)wsb;                               // 32 KB
  unsigned int* bestIdx = (unsigned int*)(wsb + 32 * 1024); // 64 KB

  const size_t statsBytes = (size_t)MROWS * NTILES * sizeof(uint2);  // 8 MB
  bool fuse = ws_size >= 96 * 1024 + statsBytes;
  uint2* stats = fuse ? (uint2*)(wsb + 96 * 1024)
                      : (uint2*)(ob + 24ull * 1024 * 1024);

  (void)hipFuncSetAttribute((const void*)k_gemm_min,
                            hipFuncAttributeMaxDynamicSharedMemorySize, 131072);

  k_conv_x  <<<4096, 256, 0, stream>>>(x, Xbf);
  k_conv_cb <<<2048, 256, 0, stream>>>(cb, Cbf, cnorm);
  k_gemm_min<<<2048, 512, 131072, stream>>>(Xbf, Cbf, cnorm, stats);
  if (fuse) {
    k_refine_gather<<<4096, 256, 0, stream>>>(x, cb, cnorm, stats, out);
  } else {
    k_refine<<<4096, 256, 0, stream>>>(x, cb, cnorm, stats, bestIdx);
    k_gather<<<4096, 256, 0, stream>>>(cb, bestIdx, out);
  }
}